// Round 12
// baseline (357.821 us; speedup 1.0000x reference)
//
#include <hip/hip_runtime.h>

typedef unsigned short u16;
typedef unsigned int   u32;
typedef __attribute__((ext_vector_type(8))) short short8;
typedef __attribute__((ext_vector_type(4))) float floatx4;
typedef __attribute__((ext_vector_type(16))) float floatx16;
typedef __attribute__((address_space(1))) const unsigned int glob_u32;
typedef __attribute__((address_space(3))) unsigned int lds_u32;

#define N_B  16
#define N_S  1024
#define N_E  8192
#define N_D  512
#define N_H  8
#define N_DK 64
#define N_L  2
#define N_N  (N_B*N_S)   /* 16384 */
#define N_BE (N_B*N_E)   /* 131072 */
#define N_COMBO 3150     /* 50*3*21 rel-combos */

__device__ __forceinline__ float bf2f(u16 u){ return __uint_as_float(((u32)u)<<16); }
__device__ __forceinline__ u16 f2bf(float f){
  u32 i = __float_as_uint(f);
  return (u16)((i + 0x7fffu + ((i>>16)&1u)) >> 16);
}

/* ---- merged setup: convert (blocks 0..8191) | transpose (8192..10239) |
   rel table (10240..11814) | zero deg (11815..11878). ---- */
#define SET_CONV 8192
#define SET_TR   (SET_CONV+2048)
#define SET_REL  (SET_TR+1575)
#define SET_ZERO (SET_REL+64)
__global__ void setup_kernel(const float* __restrict__ inp, u16* __restrict__ hb,
                             const float* __restrict__ Wq, const float* __restrict__ Wk,
                             const float* __restrict__ Wv, const float* __restrict__ Wo,
                             u16* __restrict__ WT,
                             const float* __restrict__ dre, const float* __restrict__ dae,
                             const float* __restrict__ rpe, u16* __restrict__ rel_table,
                             u32* __restrict__ deg){
  __shared__ u16 tile[32][33];
  int b = blockIdx.x, tid = threadIdx.x;
  if (b < SET_CONV){                       /* fp32 -> bf16, 4 elems/thread */
    int i = b*256 + tid;
    float4 f = ((const float4*)inp)[i];
    u16 o[4] = { f2bf(f.x), f2bf(f.y), f2bf(f.z), f2bf(f.w) };
    ((uint2*)hb)[i] = *(uint2*)o;
  } else if (b < SET_TR){                  /* weight transpose+convert */
    int z = b - SET_CONV;                  /* (16,16,8) flattened */
    int bx = (z & 15)*32, by = ((z>>4)&15)*32, zz = z>>8;
    int wsel = zz>>1, l = zz&1;
    const float* in = (wsel==0?Wq: wsel==1?Wk: wsel==2?Wv:Wo) + l*262144;
    u16* outp = WT + zz*262144;
    int tx = tid & 31, ty = tid >> 5;      /* (32,8) */
    for (int r=0;r<32;r+=8) tile[ty+r][tx] = f2bf(in[(by+ty+r)*512 + bx+tx]);
    __syncthreads();
    for (int r=0;r<32;r+=8) outp[(bx+ty+r)*512 + by+tx] = tile[tx][ty+r];
  } else if (b < SET_REL){                 /* rel table, both layers */
    int i = (b - SET_TR)*256 + tid;        /* over 2*3150*64 = 403200 exact */
    int l = i / (N_COMBO*64);
    int j = i - l*(N_COMBO*64);
    int combo = j >> 6, d = j & 63;
    int dr = combo % 50, da = (combo/50) % 3, rp = combo/150;
    rel_table[i] = f2bf(dre[l*50*64 + dr*64+d] + dae[l*3*64 + da*64+d] + rpe[l*21*64 + rp*64+d]);
  } else {                                 /* zero deg */
    int i = (b - SET_REL)*256 + tid;
    if (i < N_N) deg[i] = 0;
  }
}

/* ---------------- in-degree count ---------------- */
__global__ void count_kernel(const int* __restrict__ edge_len, const int* __restrict__ edge_index,
                             int* __restrict__ deg){
  int idx = blockIdx.x*256 + threadIdx.x;           /* over B*E */
  int b = idx >> 13, e = idx & (N_E-1);
  if (e < edge_len[b]){
    int t = edge_index[idx*2+1] + b*N_S;
    atomicAdd(&deg[t], 1);
  }
}

/* ---- exclusive scan of degrees (N = 16384 = 1024*16); also zeroes cursor ---- */
__global__ void scan_kernel(const int* __restrict__ deg, int* __restrict__ row_start,
                            int* __restrict__ cursor){
  __shared__ int sums[1024];
  int t = threadIdx.x;
  int base = t*16;
  int local[16]; int s = 0;
  for (int i=0;i<16;i++){ local[i] = s; s += deg[base+i]; }
  sums[t] = s; __syncthreads();
  for (int off=1; off<1024; off<<=1){
    int add = (t >= off) ? sums[t-off] : 0;
    __syncthreads();
    sums[t] += add;
    __syncthreads();
  }
  int prefix = (t>0) ? sums[t-1] : 0;
  for (int i=0;i<16;i++){ row_start[base+i] = prefix + local[i]; cursor[base+i] = 0; }
  if (t==1023) row_start[N_N] = sums[1023];
}

/* ---- fill CSR: packed (src, meta, flat-edge-id) int4 into CSR order.
   bstart computed inline (b<16, wave-uniform L1-hot loop); also f->tgt map ---- */
__global__ void fill_kernel(const int* __restrict__ edge_len, const int* __restrict__ edge_index,
                            const int* __restrict__ relpos_e, const int* __restrict__ deprel_e,
                            const int* __restrict__ deparc_e,
                            const int* __restrict__ row_start, int* __restrict__ cursor,
                            int4* __restrict__ csr, int* __restrict__ tgt_f){
  int idx = blockIdx.x*256 + threadIdx.x;
  int b = idx >> 13, e = idx & (N_E-1);
  if (e < edge_len[b]){
    int bs = 0;
    for (int i=0;i<b;i++) bs += edge_len[i];        /* b uniform per block */
    int f = bs + e;
    int s = edge_index[idx*2+0] + b*N_S;
    int t = edge_index[idx*2+1] + b*N_S;
    int pos = atomicAdd(&cursor[t], 1);
    int slot = row_start[t] + pos;
    int meta = deprel_e[idx] + 50*deparc_e[idx] + 150*relpos_e[idx];
    csr[slot] = make_int4(s, meta, f, 0);
    tgt_f[f]  = t;
  }
}

/* ---- MFMA GEMM v5 (unchanged, proven): 128x128x(BK=64), involution swizzle,
   32x32x16 MFMA, 8 waves/block (512 thr), wave tile 32x64.
   F32OUT=true reuses the identical path for the Wo GEMM (fp32 C). ---- */
template<bool F32OUT>
__global__ __launch_bounds__(512) void gemm_kernel(const u16* __restrict__ A,
    const u16* __restrict__ B0, const u16* __restrict__ B1, const u16* __restrict__ B2,
    void* __restrict__ C0, void* __restrict__ C1, void* __restrict__ C2){
  __shared__ __align__(16) u16 As[128*64];   /* 16KB */
  __shared__ __align__(16) u16 Bs[128*64];   /* 16KB */
  int tid  = threadIdx.x;
  int lane = tid & 63, wave = tid >> 6;      /* 8 waves */

  u32 b    = blockIdx.x + gridDim.x*(blockIdx.y + gridDim.y*blockIdx.z);
  u32 xcd  = b & 7, slot = b >> 3;
  u32 ypg  = gridDim.y >> 3;                 /* y-tiles per XCD */
  u32 my   = xcd*ypg + slot % ypg;
  u32 rest = slot / ypg;
  u32 mx   = rest % gridDim.x;
  u32 mz   = rest / gridDim.x;
  const u16* Bt = (mz==0) ? B0 : (mz==1) ? B1 : B2;
  void* C       = (mz==0) ? C0 : (mz==1) ? C1 : C2;
  int tileM = my * 128, tileN = mx * 128;

  int rbase = tid >> 3;                      /* row within g-half (0..63) */
  int scc   = (tid & 7) ^ (rbase & 7);
  const u16* gA = &A [(size_t)(tileM + rbase)*512 + scc*8];
  const u16* gB = &Bt[(size_t)(tileN + rbase)*512 + scc*8];
  u16* lA = As + (size_t)tid*8;
  u16* lB = Bs + (size_t)tid*8;

  int wm = wave >> 1, wn = wave & 1;         /* 4 row-groups x 2 col-groups */
  int l31 = lane & 31, khalf = lane >> 5;

  floatx16 acc[2];
  for (int j=0;j<2;j++)
    acc[j] = (floatx16){0.f,0.f,0.f,0.f,0.f,0.f,0.f,0.f,
                        0.f,0.f,0.f,0.f,0.f,0.f,0.f,0.f};

  for (int k0 = 0; k0 < 512; k0 += 64){
    __syncthreads();
    for (int g=0; g<2; g++){
      __builtin_amdgcn_global_load_lds((glob_u32*)(gA + (size_t)g*64*512 + k0),
                                       (lds_u32*)(lA + g*4096), 16, 0, 0);
      __builtin_amdgcn_global_load_lds((glob_u32*)(gB + (size_t)g*64*512 + k0),
                                       (lds_u32*)(lB + g*4096), 16, 0, 0);
    }
    __syncthreads();                       /* drains vmcnt: LDS tile visible */
    for (int kk=0; kk<4; kk++){
      int sw = ((kk*2 + khalf) ^ (lane & 7)) * 8;  /* swizzled chunk offset */
      short8 af, bfr[2];
      af = *(const short8*)&As[(wm*32 + l31)*64 + sw];
      for (int j=0;j<2;j++) bfr[j] = *(const short8*)&Bs[(wn*64 + j*32 + l31)*64 + sw];
      for (int j=0;j<2;j++)
        acc[j] = __builtin_amdgcn_mfma_f32_32x32x16_bf16(af, bfr[j], acc[j], 0,0,0);
    }
  }
  /* C/D layout: col = lane&31, row = (r&3) + 8*(r>>2) + 4*(lane>>5) */
  for (int j=0;j<2;j++)
    for (int r=0;r<16;r++){
      int row = tileM + wm*32 + (r&3) + 8*(r>>2) + 4*khalf;
      int col = tileN + wn*64 + j*32 + l31;
      if (F32OUT) ((float*)C)[(size_t)row*512 + col] = acc[j][r];
      else        ((u16*) C)[(size_t)row*512 + col] = f2bf(acc[j][r]);
    }
}

/* ---- streaming LN: residual + LayerNorm (+ReLU) + rescale tail ----
   wo_ln post-mortem (R6-R10): the fused GEMM+LN never got below ~40us
   (barrier-chained staging; 2.5x its 18us HBM floor across 5 variants).
   Split: Wo GEMM via the proven gemm_kernel<true> (~8.6GF -> ~12us), then
   THIS kernel streams out_pre+resid -> outf/hb at pure HBM BW (~117MB ->
   ~20us) with zero barriers. Blocks [0,4096): wave per row (R0-proven
   pattern). Blocks [4096,4608): rescale tail. */
__global__ __launch_bounds__(256) void ln_kernel(const float* __restrict__ out_pre,
    const float* __restrict__ h_in, const float* __restrict__ gamma,
    const float* __restrict__ beta,
    float* __restrict__ outf, u16* __restrict__ hb, int do_relu, int write_hb,
    float* __restrict__ attn, const int* __restrict__ tgt_f,
    const float* __restrict__ den_ws, const int* __restrict__ edge_len){
  int tid = threadIdx.x;
  if (blockIdx.x >= 4096){                    /* ---- rescale tail ---- */
    int bid2 = blockIdx.x - 4096;             /* 512 blocks x 256 thr x 2 f4 */
    int etot = 0;
    for (int b2=0;b2<N_B;b2++) etot += edge_len[b2];
    for (int rep=0; rep<2; rep++){
      int i = bid2*512 + rep*256 + tid;       /* over N_BE*2 float4s */
      int f = i >> 1;
      if (f >= etot){
        ((float4*)attn)[i] = make_float4(0.f,0.f,0.f,0.f);
      } else {
        int t = tgt_f[f];
        float4 e = ((float4*)attn)[i];
        float4 d = *(const float4*)&den_ws[t*8 + (i&1)*4];
        e.x /= (d.x + 1e-9f); e.y /= (d.y + 1e-9f);
        e.z /= (d.z + 1e-9f); e.w /= (d.w + 1e-9f);
        ((float4*)attn)[i] = e;
      }
    }
    return;
  }
  int wid  = (blockIdx.x*256 + tid) >> 6;     /* row */
  int lane = tid & 63;
  const float* xp = out_pre + (size_t)wid*512;
  const float* hp = h_in    + (size_t)wid*512;
  float x[8]; float sum = 0.f;
  for (int i=0;i<8;i++){ int c = lane + i*64; x[i] = xp[c] + hp[c]; sum += x[i]; }
  for (int o=32;o>0;o>>=1) sum += __shfl_xor(sum, o);
  float mu = sum * (1.f/512.f);
  float vs = 0.f;
  for (int i=0;i<8;i++){ float d = x[i]-mu; vs += d*d; }
  for (int o=32;o>0;o>>=1) vs += __shfl_xor(vs, o);
  float inv = rsqrtf(vs*(1.f/512.f) + 1e-5f);
  for (int i=0;i<8;i++){
    int c = lane + i*64;
    float y = (x[i]-mu)*inv*gamma[c] + beta[c];
    if (do_relu) y = fmaxf(y, 0.f);
    outf[(size_t)wid*512 + c] = y;
    if (write_hb) hb[(size_t)wid*512 + c] = f2bf(y);
  }
}

/* ---- edge attention: packed int4 csr, unroll-2.
   One wave per node, lane = (head h=lane>>3, dims d0=(lane&7)*8). Writes raw e
   to attn_out and denominator s to den_ws; rescale tail normalizes. ---- */
__global__ __launch_bounds__(256) void edge_attn_kernel(
    const u16* __restrict__ q, const u16* __restrict__ k, const u16* __restrict__ v,
    const int* __restrict__ row_start,
    const int4* __restrict__ csr, const u16* __restrict__ rel_table,
    float* __restrict__ den_ws,
    u16* __restrict__ agg, float* __restrict__ attn_out){
  int bid = blockIdx.x;
  int lb  = (bid & 7) * (gridDim.x >> 3) + (bid >> 3);   /* XCD-contiguous remap */
  int t    = lb*4 + (threadIdx.x >> 6);                  /* node */
  int lane = threadIdx.x & 63;
  int h  = lane >> 3;
  int d0 = (lane & 7) * 8;
  int rs = row_start[t], re = row_start[t+1];

  float qv[8];
  {
    uint4 qraw = *(const uint4*)&q[(size_t)t*512 + h*64 + d0];
    const u16* qp = (const u16*)&qraw;
    for (int j=0;j<8;j++) qv[j] = bf2f(qp[j]);
  }

  float s = 0.f;
  float acc[8] = {0.f,0.f,0.f,0.f,0.f,0.f,0.f,0.f};
  int idx = rs;
  for (; idx + 1 < re; idx += 2){
    int4 e0 = csr[idx], e1 = csr[idx+1];
    int sn0 = e0.x, mi0 = e0.y, f0 = e0.z;
    int sn1 = e1.x, mi1 = e1.y, f1 = e1.z;
    uint4 k0 = *(const uint4*)&k[(size_t)sn0*512 + h*64 + d0];
    uint4 v0 = *(const uint4*)&v[(size_t)sn0*512 + h*64 + d0];
    uint4 r0 = *(const uint4*)&rel_table[mi0*64 + d0];
    uint4 k1 = *(const uint4*)&k[(size_t)sn1*512 + h*64 + d0];
    uint4 v1 = *(const uint4*)&v[(size_t)sn1*512 + h*64 + d0];
    uint4 r1 = *(const uint4*)&rel_table[mi1*64 + d0];
    const u16 *kp0=(const u16*)&k0, *vp0=(const u16*)&v0, *rp0=(const u16*)&r0;
    const u16 *kp1=(const u16*)&k1, *vp1=(const u16*)&v1, *rp1=(const u16*)&r1;
    float rel0[8], rel1[8];
    for (int j=0;j<8;j++){ rel0[j]=bf2f(rp0[j]); rel1[j]=bf2f(rp1[j]); }
    float p0 = 0.f, p1 = 0.f;
    for (int j=0;j<8;j++){ p0 += qv[j]*(bf2f(kp0[j])+rel0[j]);
                           p1 += qv[j]*(bf2f(kp1[j])+rel1[j]); }
    p0 += __shfl_xor(p0,1); p1 += __shfl_xor(p1,1);
    p0 += __shfl_xor(p0,2); p1 += __shfl_xor(p1,2);
    p0 += __shfl_xor(p0,4); p1 += __shfl_xor(p1,4);
    float e0f = __expf(p0*0.125f), e1f = __expf(p1*0.125f);
    if ((lane & 7) == 0){
      attn_out[(size_t)f0*8 + h] = e0f;
      attn_out[(size_t)f1*8 + h] = e1f;
    }
    s += e0f + e1f;
    for (int j=0;j<8;j++) acc[j] += e0f*(bf2f(vp0[j])+rel0[j]) + e1f*(bf2f(vp1[j])+rel1[j]);
  }
  if (idx < re){
    int4 e0 = csr[idx];
    int sn0 = e0.x, mi0 = e0.y, f0 = e0.z;
    uint4 k0 = *(const uint4*)&k[(size_t)sn0*512 + h*64 + d0];
    uint4 v0 = *(const uint4*)&v[(size_t)sn0*512 + h*64 + d0];
    uint4 r0 = *(const uint4*)&rel_table[mi0*64 + d0];
    const u16 *kp0=(const u16*)&k0, *vp0=(const u16*)&v0, *rp0=(const u16*)&r0;
    float p0 = 0.f;
    for (int j=0;j<8;j++) p0 += qv[j]*(bf2f(kp0[j])+bf2f(rp0[j]));
    p0 += __shfl_xor(p0,1);
    p0 += __shfl_xor(p0,2);
    p0 += __shfl_xor(p0,4);
    float e0f = __expf(p0*0.125f);
    if ((lane & 7) == 0) attn_out[(size_t)f0*8 + h] = e0f;
    s += e0f;
    for (int j=0;j<8;j++) acc[j] += e0f*(bf2f(vp0[j])+bf2f(rp0[j]));
  }
  float invden = 1.f / (s + 1e-9f);
  if ((lane & 7) == 0) den_ws[t*8 + h] = s;

  u16 ob[8];
  for (int j=0;j<8;j++) ob[j] = f2bf(acc[j] * invden);
  *(uint4*)&agg[(size_t)t*512 + h*64 + d0] = *(uint4*)ob;
}

extern "C" void kernel_launch(void* const* d_in, const int* in_sizes, int n_in,
                              void* d_out, int out_size, void* d_ws, size_t ws_size,
                              hipStream_t stream){
  (void)in_sizes; (void)n_in; (void)out_size; (void)ws_size;
  const float* inp      = (const float*)d_in[0];
  const int* edge_len   = (const int*)d_in[2];
  const int* edge_index = (const int*)d_in[3];
  const int* relpos_e   = (const int*)d_in[4];
  const int* deprel_e   = (const int*)d_in[6];
  const int* deparc_e   = (const int*)d_in[7];
  const float* Wq = (const float*)d_in[14];
  const float* Wk = (const float*)d_in[15];
  const float* Wv = (const float*)d_in[16];
  const float* Wo = (const float*)d_in[17];
  const float* deprel_emb = (const float*)d_in[18];
  const float* deparc_emb = (const float*)d_in[19];
  const float* relpos_emb = (const float*)d_in[20];
  const float* ln_scale   = (const float*)d_in[21];
  const float* ln_bias    = (const float*)d_in[22];
  float* outp = (float*)d_out;

  /* ---- carve workspace (~88 MB) ---- */
  char* w = (char*)d_ws;
  auto carve = [&](size_t b)->char*{ char* p = w; w += (b + 255) & ~(size_t)255; return p; };
  u16* WT        = (u16*)carve((size_t)8*262144*2);
  int* deg       = (int*)carve((size_t)N_N*4);
  int* cursor    = (int*)carve((size_t)N_N*4);
  int* row_start = (int*)carve((size_t)(N_N+1)*4);
  int4* csr      = (int4*)carve((size_t)N_BE*16);
  int* tgt_f     = (int*)carve((size_t)N_BE*4);
  u16* rel_table = (u16*)carve((size_t)N_L*N_COMBO*64*2);
  float* den_ws  = (float*)carve((size_t)N_N*8*4);
  u16* hb        = (u16*)carve((size_t)N_N*512*2);
  u16* qb        = (u16*)carve((size_t)N_N*512*2);   /* out_pre (fp32,32MB) */
  u16* kb        = (u16*)carve((size_t)N_N*512*2);   /*   aliases qb+kb     */
  u16* vb        = (u16*)carve((size_t)N_N*512*2);
  u16* aggb      = (u16*)carve((size_t)N_N*512*2);
  float* out_pre = (float*)qb;   /* dead (post-attn) qb/kb reused per layer */

  /* ---- per-call setup (merged) ---- */
  setup_kernel<<<dim3(SET_ZERO), dim3(256), 0, stream>>>(inp, hb,
      Wq, Wk, Wv, Wo, WT, deprel_emb, deparc_emb, relpos_emb, rel_table, (u32*)deg);
  count_kernel<<<dim3(N_BE/256), dim3(256), 0, stream>>>(edge_len, edge_index, deg);
  scan_kernel<<<dim3(1), dim3(1024), 0, stream>>>(deg, row_start, cursor);
  fill_kernel<<<dim3(N_BE/256), dim3(256), 0, stream>>>(edge_len, edge_index,
      relpos_e, deprel_e, deparc_e, row_start, cursor, csr, tgt_f);

  /* ---- layers ---- */
  for (int l=0; l<N_L; l++){
    float* reps_out = outp + (size_t)l*N_N*512;
    float* attn_out = outp + (size_t)N_L*N_N*512 + (size_t)l*N_BE*N_H;
    const u16* WqT = WT + (0*2 + l)*262144;
    const u16* WkT = WT + (1*2 + l)*262144;
    const u16* WvT = WT + (2*2 + l)*262144;
    const u16* WoT = WT + (3*2 + l)*262144;

    gemm_kernel<false><<<dim3(4,128,3), dim3(512), 0, stream>>>(hb,
        WqT, WkT, WvT, (void*)qb, (void*)kb, (void*)vb);

    edge_attn_kernel<<<dim3(N_N/4), dim3(256), 0, stream>>>(qb, kb, vb,
        row_start, csr, rel_table + (size_t)l*N_COMBO*64,
        den_ws, aggb, attn_out);

    /* Wo GEMM (fp32 out) over the now-dead qb/kb region */
    gemm_kernel<true><<<dim3(4,128,1), dim3(512), 0, stream>>>(aggb,
        WoT, WoT, WoT, (void*)out_pre, (void*)out_pre, (void*)out_pre);

    /* streaming LN + residual (+ReLU) + rescale tail */
    ln_kernel<<<dim3(4096+512), dim3(256), 0, stream>>>(out_pre,
        (l==0) ? inp : outp,            /* residual: inp or reps[0] */
        ln_scale + l*512, ln_bias + l*512, reps_out, hb,
        (l==0)?1:0, (l==0)?1:0,
        attn_out, tgt_f, den_ws, edge_len);
  }
}

// Round 13
// 330.906 us; speedup vs baseline: 1.0813x; 1.0813x over previous
//
#include <hip/hip_runtime.h>

typedef unsigned short u16;
typedef unsigned int   u32;
typedef __attribute__((ext_vector_type(8))) short short8;
typedef __attribute__((ext_vector_type(4))) float floatx4;
typedef __attribute__((ext_vector_type(16))) float floatx16;
typedef __attribute__((address_space(1))) const unsigned int glob_u32;
typedef __attribute__((address_space(3))) unsigned int lds_u32;

#define N_B  16
#define N_S  1024
#define N_E  8192
#define N_D  512
#define N_H  8
#define N_DK 64
#define N_L  2
#define N_N  (N_B*N_S)   /* 16384 */
#define N_BE (N_B*N_E)   /* 131072 */
#define N_COMBO 3150     /* 50*3*21 rel-combos */

__device__ __forceinline__ float bf2f(u16 u){ return __uint_as_float(((u32)u)<<16); }
__device__ __forceinline__ u16 f2bf(float f){
  u32 i = __float_as_uint(f);
  return (u16)((i + 0x7fffu + ((i>>16)&1u)) >> 16);
}

/* ---- merged setup: convert (blocks 0..8191) | transpose (8192..10239) |
   rel table (10240..11814) | zero deg (11815..11878). ---- */
#define SET_CONV 8192
#define SET_TR   (SET_CONV+2048)
#define SET_REL  (SET_TR+1575)
#define SET_ZERO (SET_REL+64)
__global__ void setup_kernel(const float* __restrict__ inp, u16* __restrict__ hb,
                             const float* __restrict__ Wq, const float* __restrict__ Wk,
                             const float* __restrict__ Wv, const float* __restrict__ Wo,
                             u16* __restrict__ WT,
                             const float* __restrict__ dre, const float* __restrict__ dae,
                             const float* __restrict__ rpe, u16* __restrict__ rel_table,
                             u32* __restrict__ deg){
  __shared__ u16 tile[32][33];
  int b = blockIdx.x, tid = threadIdx.x;
  if (b < SET_CONV){                       /* fp32 -> bf16, 4 elems/thread */
    int i = b*256 + tid;
    float4 f = ((const float4*)inp)[i];
    u16 o[4] = { f2bf(f.x), f2bf(f.y), f2bf(f.z), f2bf(f.w) };
    ((uint2*)hb)[i] = *(uint2*)o;
  } else if (b < SET_TR){                  /* weight transpose+convert */
    int z = b - SET_CONV;                  /* (16,16,8) flattened */
    int bx = (z & 15)*32, by = ((z>>4)&15)*32, zz = z>>8;
    int wsel = zz>>1, l = zz&1;
    const float* in = (wsel==0?Wq: wsel==1?Wk: wsel==2?Wv:Wo) + l*262144;
    u16* outp = WT + zz*262144;
    int tx = tid & 31, ty = tid >> 5;      /* (32,8) */
    for (int r=0;r<32;r+=8) tile[ty+r][tx] = f2bf(in[(by+ty+r)*512 + bx+tx]);
    __syncthreads();
    for (int r=0;r<32;r+=8) outp[(bx+ty+r)*512 + by+tx] = tile[tx][ty+r];
  } else if (b < SET_REL){                 /* rel table, both layers */
    int i = (b - SET_TR)*256 + tid;        /* over 2*3150*64 = 403200 exact */
    int l = i / (N_COMBO*64);
    int j = i - l*(N_COMBO*64);
    int combo = j >> 6, d = j & 63;
    int dr = combo % 50, da = (combo/50) % 3, rp = combo/150;
    rel_table[i] = f2bf(dre[l*50*64 + dr*64+d] + dae[l*3*64 + da*64+d] + rpe[l*21*64 + rp*64+d]);
  } else {                                 /* zero deg */
    int i = (b - SET_REL)*256 + tid;
    if (i < N_N) deg[i] = 0;
  }
}

/* ---------------- in-degree count ---------------- */
__global__ void count_kernel(const int* __restrict__ edge_len, const int* __restrict__ edge_index,
                             int* __restrict__ deg){
  int idx = blockIdx.x*256 + threadIdx.x;           /* over B*E */
  int b = idx >> 13, e = idx & (N_E-1);
  if (e < edge_len[b]){
    int t = edge_index[idx*2+1] + b*N_S;
    atomicAdd(&deg[t], 1);
  }
}

/* ---- exclusive scan of degrees (N = 16384 = 1024*16); also zeroes cursor ---- */
__global__ void scan_kernel(const int* __restrict__ deg, int* __restrict__ row_start,
                            int* __restrict__ cursor){
  __shared__ int sums[1024];
  int t = threadIdx.x;
  int base = t*16;
  int local[16]; int s = 0;
  for (int i=0;i<16;i++){ local[i] = s; s += deg[base+i]; }
  sums[t] = s; __syncthreads();
  for (int off=1; off<1024; off<<=1){
    int add = (t >= off) ? sums[t-off] : 0;
    __syncthreads();
    sums[t] += add;
    __syncthreads();
  }
  int prefix = (t>0) ? sums[t-1] : 0;
  for (int i=0;i<16;i++){ row_start[base+i] = prefix + local[i]; cursor[base+i] = 0; }
  if (t==1023) row_start[N_N] = sums[1023];
}

/* ---- fill CSR: packed (src, meta, flat-edge-id) int4 into CSR order.
   bstart computed inline (b<16, wave-uniform L1-hot loop); also f->tgt map ---- */
__global__ void fill_kernel(const int* __restrict__ edge_len, const int* __restrict__ edge_index,
                            const int* __restrict__ relpos_e, const int* __restrict__ deprel_e,
                            const int* __restrict__ deparc_e,
                            const int* __restrict__ row_start, int* __restrict__ cursor,
                            int4* __restrict__ csr, int* __restrict__ tgt_f){
  int idx = blockIdx.x*256 + threadIdx.x;
  int b = idx >> 13, e = idx & (N_E-1);
  if (e < edge_len[b]){
    int bs = 0;
    for (int i=0;i<b;i++) bs += edge_len[i];        /* b uniform per block */
    int f = bs + e;
    int s = edge_index[idx*2+0] + b*N_S;
    int t = edge_index[idx*2+1] + b*N_S;
    int pos = atomicAdd(&cursor[t], 1);
    int slot = row_start[t] + pos;
    int meta = deprel_e[idx] + 50*deparc_e[idx] + 150*relpos_e[idx];
    csr[slot] = make_int4(s, meta, f, 0);
    tgt_f[f]  = t;
  }
}

/* ---- MFMA GEMM v5: 128x128x(BK=64), involution swizzle, 32x32x16 MFMA,
   8 waves/block (512 thr), wave tile 32x64. Best-measured config (R6). ---- */
template<bool F32OUT>
__global__ __launch_bounds__(512) void gemm_kernel(const u16* __restrict__ A,
    const u16* __restrict__ B0, const u16* __restrict__ B1, const u16* __restrict__ B2,
    void* __restrict__ C0, void* __restrict__ C1, void* __restrict__ C2){
  __shared__ __align__(16) u16 As[128*64];   /* 16KB */
  __shared__ __align__(16) u16 Bs[128*64];   /* 16KB */
  int tid  = threadIdx.x;
  int lane = tid & 63, wave = tid >> 6;      /* 8 waves */

  u32 b    = blockIdx.x + gridDim.x*(blockIdx.y + gridDim.y*blockIdx.z);
  u32 xcd  = b & 7, slot = b >> 3;
  u32 ypg  = gridDim.y >> 3;                 /* y-tiles per XCD */
  u32 my   = xcd*ypg + slot % ypg;
  u32 rest = slot / ypg;
  u32 mx   = rest % gridDim.x;
  u32 mz   = rest / gridDim.x;
  const u16* Bt = (mz==0) ? B0 : (mz==1) ? B1 : B2;
  void* C       = (mz==0) ? C0 : (mz==1) ? C1 : C2;
  int tileM = my * 128, tileN = mx * 128;

  int rbase = tid >> 3;                      /* row within g-half (0..63) */
  int scc   = (tid & 7) ^ (rbase & 7);
  const u16* gA = &A [(size_t)(tileM + rbase)*512 + scc*8];
  const u16* gB = &Bt[(size_t)(tileN + rbase)*512 + scc*8];
  u16* lA = As + (size_t)tid*8;
  u16* lB = Bs + (size_t)tid*8;

  int wm = wave >> 1, wn = wave & 1;         /* 4 row-groups x 2 col-groups */
  int l31 = lane & 31, khalf = lane >> 5;

  floatx16 acc[2];
  for (int j=0;j<2;j++)
    acc[j] = (floatx16){0.f,0.f,0.f,0.f,0.f,0.f,0.f,0.f,
                        0.f,0.f,0.f,0.f,0.f,0.f,0.f,0.f};

  for (int k0 = 0; k0 < 512; k0 += 64){
    __syncthreads();
    for (int g=0; g<2; g++){
      __builtin_amdgcn_global_load_lds((glob_u32*)(gA + (size_t)g*64*512 + k0),
                                       (lds_u32*)(lA + g*4096), 16, 0, 0);
      __builtin_amdgcn_global_load_lds((glob_u32*)(gB + (size_t)g*64*512 + k0),
                                       (lds_u32*)(lB + g*4096), 16, 0, 0);
    }
    __syncthreads();                       /* drains vmcnt: LDS tile visible */
    for (int kk=0; kk<4; kk++){
      int sw = ((kk*2 + khalf) ^ (lane & 7)) * 8;  /* swizzled chunk offset */
      short8 af, bfr[2];
      af = *(const short8*)&As[(wm*32 + l31)*64 + sw];
      for (int j=0;j<2;j++) bfr[j] = *(const short8*)&Bs[(wn*64 + j*32 + l31)*64 + sw];
      for (int j=0;j<2;j++)
        acc[j] = __builtin_amdgcn_mfma_f32_32x32x16_bf16(af, bfr[j], acc[j], 0,0,0);
    }
  }
  /* C/D layout: col = lane&31, row = (r&3) + 8*(r>>2) + 4*(lane>>5) */
  for (int j=0;j<2;j++)
    for (int r=0;r<16;r++){
      int row = tileM + wm*32 + (r&3) + 8*(r>>2) + 4*khalf;
      int col = tileN + wn*64 + j*32 + l31;
      if (F32OUT) ((float*)C)[(size_t)row*512 + col] = acc[j][r];
      else        ((u16*) C)[(size_t)row*512 + col] = f2bf(acc[j][r]);
    }
}

/* ---- fused Wo-GEMM + residual + LayerNorm (+ReLU) + rescale tail ----
   Best-measured config (R6, 337.8 total): BM=32, BK=64, 3-bit involution
   swizzle, 8 waves, (512,2), rescale tail rides as blocks [512,768). ---- */
__global__ __launch_bounds__(512,2) void wo_ln_kernel(const u16* __restrict__ A,
    const u16* __restrict__ Bt, const float* __restrict__ resid,
    const float* __restrict__ gamma, const float* __restrict__ beta,
    float* __restrict__ outf, u16* __restrict__ hb, int do_relu, int write_hb,
    float* __restrict__ attn, const int* __restrict__ tgt_f,
    const float* __restrict__ den_ws, const int* __restrict__ edge_len){
  __shared__ __align__(16) u16 As[32*64];     /* 4KB  */
  __shared__ __align__(16) u16 Bs[512*64];    /* 64KB */
  __shared__ float pSum[32][8], pSq[32][8], muL[32], invL[32];
  int tid  = threadIdx.x;

  if (blockIdx.x >= 512){                     /* ---- rescale tail ---- */
    int bid2 = blockIdx.x - 512;              /* 256 blocks x 512 thr x 2 f4 */
    int etot = 0;
    for (int b2=0;b2<N_B;b2++) etot += edge_len[b2];
    for (int rep=0; rep<2; rep++){
      int i = bid2*1024 + rep*512 + tid;      /* over N_BE*2 float4s */
      int f = i >> 1;
      if (f >= etot){
        ((float4*)attn)[i] = make_float4(0.f,0.f,0.f,0.f);
      } else {
        int t = tgt_f[f];
        float4 e = ((float4*)attn)[i];
        float4 d = *(const float4*)&den_ws[t*8 + (i&1)*4];
        e.x /= (d.x + 1e-9f); e.y /= (d.y + 1e-9f);
        e.z /= (d.z + 1e-9f); e.w /= (d.w + 1e-9f);
        ((float4*)attn)[i] = e;
      }
    }
    return;
  }

  int lane = tid & 63, wave = tid >> 6;
  int quad = lane >> 4, l16 = lane & 15;
  int R = blockIdx.x * 32;

  /* A: 256 chunks (32 rows x 8); tid<256 stages chunk tid.
     B: 4096 chunks (512 rows x 8); 8 per thread.
     LDS[row][cc] = G[row][cc ^ (row&7)]  (involution). */
  const u16* gA = A; u16* lA = As;
  if (tid < 256){
    int row = tid >> 3, cc = tid & 7;
    gA = A + (size_t)(R + row)*512 + (cc ^ (row & 7))*8;
    lA = As + tid*8;
  }
  const u16* gB[8]; u16* lB[8];
  for (int m=0;m<8;m++){
    int c = m*512 + tid;
    int row = c >> 3, cc = c & 7;
    gB[m] = Bt + (size_t)row*512 + (cc ^ (row & 7))*8;
    lB[m] = Bs + c*8;
  }

  floatx4 acc[2][4];
  for (int i=0;i<2;i++) for (int j=0;j<4;j++) acc[i][j] = (floatx4){0.f,0.f,0.f,0.f};

  for (int k0 = 0; k0 < 512; k0 += 64){
    __syncthreads();
    if (tid < 256)
      __builtin_amdgcn_global_load_lds((glob_u32*)(gA + k0), (lds_u32*)lA, 16, 0, 0);
    for (int m=0;m<8;m++)
      __builtin_amdgcn_global_load_lds((glob_u32*)(gB[m] + k0), (lds_u32*)lB[m], 16, 0, 0);
    __syncthreads();
    for (int kk=0; kk<2; kk++){
      int sw = ((kk*4 + quad) ^ (l16 & 7)) * 8;
      short8 af[2], bfr[4];
      for (int i=0;i<2;i++) af [i] = *(const short8*)&As[(i*16 + l16)*64 + sw];
      for (int j=0;j<4;j++) bfr[j] = *(const short8*)&Bs[(wave*64 + j*16 + l16)*64 + sw];
      for (int i=0;i<2;i++)
        for (int j=0;j<4;j++)
          acc[i][j] = __builtin_amdgcn_mfma_f32_16x16x32_bf16(af[i], bfr[j], acc[i][j], 0,0,0);
    }
  }

  /* residual add in place (C/D layout: col=l16, row=quad*4+r) */
  for (int i=0;i<2;i++)
    for (int j=0;j<4;j++){
      int col = wave*64 + j*16 + l16;
      for (int r=0;r<4;r++){
        int row = R + i*16 + quad*4 + r;
        acc[i][j][r] += resid[(size_t)row*512 + col];
      }
    }
  /* per-row partial stats: sum over j (4 cols/lane), then 16-lane shfl */
  for (int i=0;i<2;i++)
    for (int r=0;r<4;r++){
      float s = acc[i][0][r] + acc[i][1][r] + acc[i][2][r] + acc[i][3][r];
      float q = acc[i][0][r]*acc[i][0][r] + acc[i][1][r]*acc[i][1][r]
              + acc[i][2][r]*acc[i][2][r] + acc[i][3][r]*acc[i][3][r];
      for (int o=1;o<16;o<<=1){ s += __shfl_xor(s,o); q += __shfl_xor(q,o); }
      if (l16 == 0){
        int lrow = i*16 + quad*4 + r;
        pSum[lrow][wave] = s;
        pSq [lrow][wave] = q;
      }
    }
  __syncthreads();
  if (tid < 32){
    float s=0.f, q=0.f;
    for (int w2=0; w2<8; w2++){ s += pSum[tid][w2]; q += pSq[tid][w2]; }
    float mu   = s * (1.f/512.f);
    float varr = q * (1.f/512.f) - mu*mu;
    muL [tid] = mu;
    invL[tid] = rsqrtf(varr + 1e-5f);
  }
  __syncthreads();
  for (int i=0;i<2;i++)
    for (int j=0;j<4;j++){
      int col = wave*64 + j*16 + l16;
      float g = gamma[col], bb = beta[col];
      for (int r=0;r<4;r++){
        int lrow = i*16 + quad*4 + r;
        int row  = R + lrow;
        float y = (acc[i][j][r] - muL[lrow]) * invL[lrow] * g + bb;
        if (do_relu) y = fmaxf(y, 0.f);
        outf[(size_t)row*512 + col] = y;
        if (write_hb) hb[(size_t)row*512 + col] = f2bf(y);
      }
    }
}

/* ---- edge attention: packed int4 csr, unroll-2.
   One wave per node, lane = (head h=lane>>3, dims d0=(lane&7)*8). Writes raw e
   to attn_out and denominator s to den_ws; rescale tail normalizes. ---- */
__global__ __launch_bounds__(256) void edge_attn_kernel(
    const u16* __restrict__ q, const u16* __restrict__ k, const u16* __restrict__ v,
    const int* __restrict__ row_start,
    const int4* __restrict__ csr, const u16* __restrict__ rel_table,
    float* __restrict__ den_ws,
    u16* __restrict__ agg, float* __restrict__ attn_out){
  int bid = blockIdx.x;
  int lb  = (bid & 7) * (gridDim.x >> 3) + (bid >> 3);   /* XCD-contiguous remap */
  int t    = lb*4 + (threadIdx.x >> 6);                  /* node */
  int lane = threadIdx.x & 63;
  int h  = lane >> 3;
  int d0 = (lane & 7) * 8;
  int rs = row_start[t], re = row_start[t+1];

  float qv[8];
  {
    uint4 qraw = *(const uint4*)&q[(size_t)t*512 + h*64 + d0];
    const u16* qp = (const u16*)&qraw;
    for (int j=0;j<8;j++) qv[j] = bf2f(qp[j]);
  }

  float s = 0.f;
  float acc[8] = {0.f,0.f,0.f,0.f,0.f,0.f,0.f,0.f};
  int idx = rs;
  for (; idx + 1 < re; idx += 2){
    int4 e0 = csr[idx], e1 = csr[idx+1];
    int sn0 = e0.x, mi0 = e0.y, f0 = e0.z;
    int sn1 = e1.x, mi1 = e1.y, f1 = e1.z;
    uint4 k0 = *(const uint4*)&k[(size_t)sn0*512 + h*64 + d0];
    uint4 v0 = *(const uint4*)&v[(size_t)sn0*512 + h*64 + d0];
    uint4 r0 = *(const uint4*)&rel_table[mi0*64 + d0];
    uint4 k1 = *(const uint4*)&k[(size_t)sn1*512 + h*64 + d0];
    uint4 v1 = *(const uint4*)&v[(size_t)sn1*512 + h*64 + d0];
    uint4 r1 = *(const uint4*)&rel_table[mi1*64 + d0];
    const u16 *kp0=(const u16*)&k0, *vp0=(const u16*)&v0, *rp0=(const u16*)&r0;
    const u16 *kp1=(const u16*)&k1, *vp1=(const u16*)&v1, *rp1=(const u16*)&r1;
    float rel0[8], rel1[8];
    for (int j=0;j<8;j++){ rel0[j]=bf2f(rp0[j]); rel1[j]=bf2f(rp1[j]); }
    float p0 = 0.f, p1 = 0.f;
    for (int j=0;j<8;j++){ p0 += qv[j]*(bf2f(kp0[j])+rel0[j]);
                           p1 += qv[j]*(bf2f(kp1[j])+rel1[j]); }
    p0 += __shfl_xor(p0,1); p1 += __shfl_xor(p1,1);
    p0 += __shfl_xor(p0,2); p1 += __shfl_xor(p1,2);
    p0 += __shfl_xor(p0,4); p1 += __shfl_xor(p1,4);
    float e0f = __expf(p0*0.125f), e1f = __expf(p1*0.125f);
    if ((lane & 7) == 0){
      attn_out[(size_t)f0*8 + h] = e0f;
      attn_out[(size_t)f1*8 + h] = e1f;
    }
    s += e0f + e1f;
    for (int j=0;j<8;j++) acc[j] += e0f*(bf2f(vp0[j])+rel0[j]) + e1f*(bf2f(vp1[j])+rel1[j]);
  }
  if (idx < re){
    int4 e0 = csr[idx];
    int sn0 = e0.x, mi0 = e0.y, f0 = e0.z;
    uint4 k0 = *(const uint4*)&k[(size_t)sn0*512 + h*64 + d0];
    uint4 v0 = *(const uint4*)&v[(size_t)sn0*512 + h*64 + d0];
    uint4 r0 = *(const uint4*)&rel_table[mi0*64 + d0];
    const u16 *kp0=(const u16*)&k0, *vp0=(const u16*)&v0, *rp0=(const u16*)&r0;
    float p0 = 0.f;
    for (int j=0;j<8;j++) p0 += qv[j]*(bf2f(kp0[j])+bf2f(rp0[j]));
    p0 += __shfl_xor(p0,1);
    p0 += __shfl_xor(p0,2);
    p0 += __shfl_xor(p0,4);
    float e0f = __expf(p0*0.125f);
    if ((lane & 7) == 0) attn_out[(size_t)f0*8 + h] = e0f;
    s += e0f;
    for (int j=0;j<8;j++) acc[j] += e0f*(bf2f(vp0[j])+bf2f(rp0[j]));
  }
  float invden = 1.f / (s + 1e-9f);
  if ((lane & 7) == 0) den_ws[t*8 + h] = s;

  u16 ob[8];
  for (int j=0;j<8;j++) ob[j] = f2bf(acc[j] * invden);
  *(uint4*)&agg[(size_t)t*512 + h*64 + d0] = *(uint4*)ob;
}

extern "C" void kernel_launch(void* const* d_in, const int* in_sizes, int n_in,
                              void* d_out, int out_size, void* d_ws, size_t ws_size,
                              hipStream_t stream){
  (void)in_sizes; (void)n_in; (void)out_size; (void)ws_size;
  const float* inp      = (const float*)d_in[0];
  const int* edge_len   = (const int*)d_in[2];
  const int* edge_index = (const int*)d_in[3];
  const int* relpos_e   = (const int*)d_in[4];
  const int* deprel_e   = (const int*)d_in[6];
  const int* deparc_e   = (const int*)d_in[7];
  const float* Wq = (const float*)d_in[14];
  const float* Wk = (const float*)d_in[15];
  const float* Wv = (const float*)d_in[16];
  const float* Wo = (const float*)d_in[17];
  const float* deprel_emb = (const float*)d_in[18];
  const float* deparc_emb = (const float*)d_in[19];
  const float* relpos_emb = (const float*)d_in[20];
  const float* ln_scale   = (const float*)d_in[21];
  const float* ln_bias    = (const float*)d_in[22];
  float* outp = (float*)d_out;

  /* ---- carve workspace (~88 MB) ---- */
  char* w = (char*)d_ws;
  auto carve = [&](size_t b)->char*{ char* p = w; w += (b + 255) & ~(size_t)255; return p; };
  u16* WT        = (u16*)carve((size_t)8*262144*2);
  int* deg       = (int*)carve((size_t)N_N*4);
  int* cursor    = (int*)carve((size_t)N_N*4);
  int* row_start = (int*)carve((size_t)(N_N+1)*4);
  int4* csr      = (int4*)carve((size_t)N_BE*16);
  int* tgt_f     = (int*)carve((size_t)N_BE*4);
  u16* rel_table = (u16*)carve((size_t)N_L*N_COMBO*64*2);
  float* den_ws  = (float*)carve((size_t)N_N*8*4);
  u16* hb        = (u16*)carve((size_t)N_N*512*2);
  u16* qb        = (u16*)carve((size_t)N_N*512*2);
  u16* kb        = (u16*)carve((size_t)N_N*512*2);
  u16* vb        = (u16*)carve((size_t)N_N*512*2);
  u16* aggb      = (u16*)carve((size_t)N_N*512*2);

  /* ---- per-call setup (merged) ---- */
  setup_kernel<<<dim3(SET_ZERO), dim3(256), 0, stream>>>(inp, hb,
      Wq, Wk, Wv, Wo, WT, deprel_emb, deparc_emb, relpos_emb, rel_table, (u32*)deg);
  count_kernel<<<dim3(N_BE/256), dim3(256), 0, stream>>>(edge_len, edge_index, deg);
  scan_kernel<<<dim3(1), dim3(1024), 0, stream>>>(deg, row_start, cursor);
  fill_kernel<<<dim3(N_BE/256), dim3(256), 0, stream>>>(edge_len, edge_index,
      relpos_e, deprel_e, deparc_e, row_start, cursor, csr, tgt_f);

  /* ---- layers ---- */
  for (int l=0; l<N_L; l++){
    float* reps_out = outp + (size_t)l*N_N*512;
    float* attn_out = outp + (size_t)N_L*N_N*512 + (size_t)l*N_BE*N_H;
    const u16* WqT = WT + (0*2 + l)*262144;
    const u16* WkT = WT + (1*2 + l)*262144;
    const u16* WvT = WT + (2*2 + l)*262144;
    const u16* WoT = WT + (3*2 + l)*262144;

    gemm_kernel<false><<<dim3(4,128,3), dim3(512), 0, stream>>>(hb,
        WqT, WkT, WvT, (void*)qb, (void*)kb, (void*)vb);

    edge_attn_kernel<<<dim3(N_N/4), dim3(256), 0, stream>>>(qb, kb, vb,
        row_start, csr, rel_table + (size_t)l*N_COMBO*64,
        den_ws, aggb, attn_out);

    wo_ln_kernel<<<dim3(512+256), dim3(512), 0, stream>>>(aggb, WoT,
        (l==0) ? inp : outp,            /* residual: inp or reps[0] */
        ln_scale + l*512, ln_bias + l*512, reps_out, hb,
        (l==0)?1:0, (l==0)?1:0,
        attn_out, tgt_f, den_ws, edge_len);
  }
}